// Round 9
// baseline (43.781 us; speedup 1.0000x reference)
//
#include <hip/hip_runtime.h>
#include <hip/hip_bf16.h>

// MCorrLCorr via bf16 MFMA GEMM, per (b,hx) block (512 blocks, 2/CU), SINGLE KERNEL:
//   out[b,o,hx,hy] = sum_{c,fx,fy} in[b,c,(hx+1)(fx+1)-1, 2hy+fy-2] * w[o,c,fx,fy] + bias[o]
// GEMM: C[o,hy] = A[o,k]*B[k,hy], k = c*32+fx*8+fy (K=1024).
// 8 waves = 2 o-halves x 4 hy-quarters (32o x 48hy per wave, mt2/tt3), full K per wave.
// wprep FUSED (eliminates the separate dispatch + inter-kernel gap, the one feature
// common to all nine 32.7-34 variants): per iter each block stages its 16 KB A-tile
// by COALESCED fp32 reads of w (16 o-rows x 512 B contiguous per round, 4 rounds --
// NOT R3's 4KB-stride lane pattern), converts in-register, ds_write_b64 into the
// wl-layout A-LDS that R6 proved perf-neutral to read. Write-bank XOR o^=(gl&7)
// spreads the 16-way write conflict to 2-way (free); reads stay 2-way.
// B: staged X rows in LDS (stride 200 dwords -> 2-way = free), double-buffered,
// 2-deep X prefetch; sync = s_barrier + lgkmcnt(0) only (vmcnt stays counted:
// A(t+1)+X(t+2) issue before COMPUTE; ACOMMIT waits vmcnt(3), nothing drains).

#define Bb   16
#define NGX  128
#define NGY  384
#define Oo   64
#define NHX  32
#define NHY  190

#define HEAD 4                   // head pad shorts (8B-aligned data start)
#define RSX  400                 // X row stride in shorts = 200 dwords (4 head + 384 + 12 pad)
#define XBUF (16 * RSX)          // shorts per X buffer (16 rows/iter)
#define ATIL 8192                // shorts per A buffer (16 octet-groups x 64o x 8)

typedef short bf16x8 __attribute__((ext_vector_type(8)));
typedef float f32x4  __attribute__((ext_vector_type(4)));
typedef unsigned short u16x4 __attribute__((ext_vector_type(4)));

__device__ __forceinline__ unsigned short f2bf(float f) {
  __hip_bfloat16 h = __float2bfloat16(f);
  return __builtin_bit_cast(unsigned short, h);
}

__global__ __launch_bounds__(512, 4)
void mcorr_mfma_kernel(const float* __restrict__ in, const float* __restrict__ w,
                       const float* __restrict__ bias, float* __restrict__ out) {
  const int tid  = threadIdx.x;
  const int l    = tid & 63;
  const int wv   = tid >> 6;          // 8 waves
  const int wo   = wv >> 2;           // o half: o in [32*wo, 32*wo+32)
  const int whq  = wv & 3;            // hy quarter: hy in [48*whq, 48*whq+48)
  const int lo16 = l & 15, gq = l >> 4;
  const int l5   = tid & 31;          // A-staging lane within 32-group
  const int og   = tid >> 5;          // A-staging o-group 0..15

  // XCD swizzle: XCD x gets 2 consecutive b's worth of blocks (all hx -> L2 row reuse)
  int lid = blockIdx.x + NHX * blockIdx.y;
  int swz = (lid & 7) * 64 + (lid >> 3);
  const int hx = swz & 31;
  const int b  = swz >> 5;

  __shared__ __align__(16) unsigned short smem[2 * ATIL + 2 * XBUF];  // 57.6 KB
  unsigned short* As_ = smem;               // [2 buf][16 gl][64 o'][8]
  unsigned short* xs_ = smem + 2 * ATIL;    // [2 buf][16 rows][400]

  f32x4 acc[2][3];
  #pragma unroll
  for (int i = 0; i < 2; ++i)
    #pragma unroll
    for (int j = 0; j < 3; ++j) acc[i][j] = (f32x4){0.f, 0.f, 0.f, 0.f};

  // zero X pad regions once: shorts [0,HEAD) and [388,400) per row per buffer
  {
    int bu = tid >> 8, row = (tid >> 4) & 15, j = tid & 15;
    xs_[bu * XBUF + row * RSX + (j < HEAD ? j : 384 + j)] = 0;
  }

  // X staging: 32 threads per row r_st = c_local*4 + fx (16 rows per iter)
  const int r_st  = tid >> 5;
  const int fx_st = r_st & 3;
  const int c_st  = r_st >> 2;                             // channel = 4t + c_st
  const int gx_st = (hx + 1) * (fx_st + 1) - 1;            // always in [0, NGX)
  const float* xbase = in + (((size_t)b * 32 + c_st) * NGX + gx_st) * NGY;
  const size_t cstep = (size_t)4 * NGX * NGY;              // +4 c per iter

  float4 xv[2][3];                                         // 2-deep X prefetch sets
  float4 av[4];                                            // A-tile staging (1 iter)

  // ---- A staging: iter-t tile = w[o][128t .. 128t+128), all 64 o (16 KB bf16) ----
  // round r: o = 16r + og, lane l5 reads 4 floats at 128t + 4*l5 (512 B/row,
  // 32-lane contiguous -> perfect dwordx4 coalescing; w is L2-hot after iter 0).
#define ALOAD(T) do {                                                    \
    _Pragma("unroll") for (int r_ = 0; r_ < 4; ++r_)                     \
      av[r_] = *(const float4*)(w + (size_t)(16 * r_ + og) * 1024 +      \
                                128 * (T) + 4 * l5);                     \
  } while (0)

  // dst: k_local = 4*l5 + i -> octet gl = l5>>1, j = 4*(l5&1)+i; o' = o ^ (gl&7)
  // (write banks 2-way instead of 16-way; reads apply the same XOR).
#define ACOMMIT(T) do {                                                  \
    unsigned short* Ad_ = As_ + ((T) & 1) * ATIL;                        \
    const int gl_ = l5 >> 1;                                             \
    _Pragma("unroll") for (int r_ = 0; r_ < 4; ++r_) {                   \
      int op_ = (16 * r_ + og) ^ (gl_ & 7);                              \
      u16x4 h_;                                                          \
      h_[0] = f2bf(av[r_].x); h_[1] = f2bf(av[r_].y);                    \
      h_[2] = f2bf(av[r_].z); h_[3] = f2bf(av[r_].w);                    \
      *(u16x4*)&Ad_[gl_ * 512 + op_ * 8 + 4 * (l5 & 1)] = h_;            \
    }                                                                    \
  } while (0)

#define XLOAD(T) do {                                                    \
    const float* xb_ = xbase + (size_t)(T) * cstep;                      \
    _Pragma("unroll") for (int s_ = 0; s_ < 3; ++s_)                     \
      xv[(T) & 1][s_] = *(const float4*)(xb_ + 4 * l5 + 128 * s_);       \
  } while (0)

#define XCOMMIT(T) do {                                                  \
    unsigned short* row_ = xs_ + ((T) & 1) * XBUF + r_st * RSX;          \
    _Pragma("unroll") for (int s_ = 0; s_ < 3; ++s_) {                   \
      u16x4 h_;                                                          \
      h_[0] = f2bf(xv[(T) & 1][s_].x); h_[1] = f2bf(xv[(T) & 1][s_].y);  \
      h_[2] = f2bf(xv[(T) & 1][s_].z); h_[3] = f2bf(xv[(T) & 1][s_].w);  \
      *(u16x4*)&row_[HEAD + 4 * l5 + 128 * s_] = h_;                     \
    }                                                                    \
  } while (0)

  // raw barrier: drain LDS writes only; global loads stay in flight across it
#define BAR() do {                                                       \
    asm volatile("s_waitcnt lgkmcnt(0)" ::: "memory");                   \
    __builtin_amdgcn_s_barrier();                                        \
  } while (0)

#define COMPUTE(T) do {                                                              \
    const unsigned short* Ab_ = As_ + ((T) & 1) * ATIL;                              \
    const unsigned* Xb_ = (const unsigned*)(xs_ + ((T) & 1) * XBUF);                 \
    _Pragma("unroll") for (int cs_ = 0; cs_ < 4; ++cs_) {                            \
      const int gl_ = 4 * cs_ + gq;                                                  \
      const unsigned short* ap_ =                                                    \
          Ab_ + gl_ * 512 + ((32 * wo + lo16) ^ (gl_ & 7)) * 8;                      \
      bf16x8 a0_ = *(const bf16x8*)ap_;                                              \
      bf16x8 a1_ = *(const bf16x8*)(ap_ + 128);   /* (o+16)^p = o^p+16, p<8 */       \
      const int r_ = cs_ * 4 + gq;                                                   \
      _Pragma("unroll") for (int tt_ = 0; tt_ < 3; ++tt_) {                          \
        int hy_ = 48 * whq + 16 * tt_ + lo16;                                        \
        const unsigned* xp_ = &Xb_[r_ * 200 + 1 + hy_];                              \
        union { unsigned u[4]; bf16x8 v; } bb_;                                      \
        bb_.u[0] = xp_[0]; bb_.u[1] = xp_[1];                                        \
        bb_.u[2] = xp_[2]; bb_.u[3] = xp_[3];                                        \
        acc[0][tt_] = __builtin_amdgcn_mfma_f32_16x16x32_bf16(                       \
            a0_, bb_.v, acc[0][tt_], 0, 0, 0);                                       \
        acc[1][tt_] = __builtin_amdgcn_mfma_f32_16x16x32_bf16(                       \
            a1_, bb_.v, acc[1][tt_], 0, 0, 0);                                       \
      }                                                                              \
    }                                                                                \
  } while (0)

  // ---- prologue: A(0) + X(0),X(1) issue; commit A(0),X(0); publish ----
  ALOAD(0);                  // 4 vmem (oldest)
  XLOAD(0);                  // 3 vmem
  XLOAD(1);                  // 3 vmem
  ACOMMIT(0);                // waits vmcnt(6): A(0) done, X(0),X(1) in flight
  XCOMMIT(0);                // waits vmcnt(3): X(0) done, X(1) in flight
  BAR();

  // ---- main loop: 8 iterations, one lgkm-only barrier each ----
  #pragma unroll
  for (int t = 0; t < 8; ++t) {
    if (t < 7) ALOAD(t + 1);             // 4 vmem, lands during COMPUTE(t)
    if (t < 6) XLOAD(t + 2);             // 3 vmem, flies across 2 barriers
    __builtin_amdgcn_sched_barrier(0);   // pin: issue loads before compute
    COMPUTE(t);                          // ds_read A+B frags + MFMA (lgkm counted)
    if (t < 7) {
      ACOMMIT(t + 1);                    // waits vmcnt(3): X(t+2) stays in flight
      XCOMMIT(t + 1);                    // X(t+1) older than A(t+1): already done
      BAR();
    }
  }

  // ---- epilogue: bias + store ----
  #pragma unroll
  for (int mt = 0; mt < 2; ++mt) {
    #pragma unroll
    for (int reg = 0; reg < 4; ++reg) {
      int o = 32 * wo + 16 * mt + 4 * gq + reg;
      float bv = bias[o];
      #pragma unroll
      for (int tt = 0; tt < 3; ++tt) {
        int hy = 48 * whq + 16 * tt + lo16;
        if (hy < NHY)
          out[(((size_t)b * Oo + o) * NHX + hx) * NHY + hy] = acc[mt][tt][reg] + bv;
      }
    }
  }
}

extern "C" void kernel_launch(void* const* d_in, const int* in_sizes, int n_in,
                              void* d_out, int out_size, void* d_ws, size_t ws_size,
                              hipStream_t stream) {
  const float* in   = (const float*)d_in[0];
  const float* w    = (const float*)d_in[1];
  const float* bias = (const float*)d_in[2];
  float* out = (float*)d_out;

  dim3 grid(NHX, Bb);
  mcorr_mfma_kernel<<<grid, 512, 0, stream>>>(in, w, bias, out);
}